// Round 6
// baseline (429.029 us; speedup 1.0000x reference)
//
#include <hip/hip_runtime.h>

typedef unsigned short ushort_t;
typedef __attribute__((ext_vector_type(8))) short short8;
typedef __attribute__((ext_vector_type(4))) float f32x4;
typedef __attribute__((ext_vector_type(4))) int int4v;

#define RNUM 8
#define FDIM 128

__device__ __forceinline__ float bf2f(ushort_t u) {
    union { unsigned int i; float f; } x;
    x.i = ((unsigned int)u) << 16;
    return x.f;
}
__device__ __forceinline__ ushort_t f2bf(float f) {
    union { float f; unsigned int i; } x;
    x.f = f;
    unsigned int u = x.i;
    u += 0x7fffu + ((u >> 16) & 1u);   // round-to-nearest-even
    return (ushort_t)(u >> 16);
}

// async global->LDS, 16B per lane; LDS dest is wave-uniform base + lane*16
__device__ __forceinline__ void gl_lds16(const void* g, void* s) {
    __builtin_amdgcn_global_load_lds(
        (const __attribute__((address_space(1))) unsigned int*)g,
        (__attribute__((address_space(3))) unsigned int*)s, 16, 0, 0);
}

// ---------------- linked-list segment index ----------------
// head[seg] (memset to -1 via hipMemsetAsync) -> most recent edge id;
// nxt[i] -> previous edge with same seg. Coalesced writes only.

__global__ void link_kernel(const int* __restrict__ dst, const int* __restrict__ et,
                            int* head, int* __restrict__ nxt, int E) {
    int i = blockIdx.x * 256 + threadIdx.x;
    if (i < E) {
        int seg = dst[i] * RNUM + et[i];
        nxt[i] = atomicExch(&head[seg], i);
    }
}

// ------- weight transpose + bf16 cast: Wt[r][h][f] = bf16(W[r][f][h]), r=8 -> root -------

__global__ __launch_bounds__(256) void transpose_w(const float* __restrict__ rel_w,
                                                   const float* __restrict__ root_w,
                                                   ushort_t* __restrict__ Wt) {
    int r = blockIdx.x;  // 0..8
    const float* src = (r < 8) ? (rel_w + r * 16384) : root_w;
    __shared__ ushort_t t[128 * 130];
    for (int idx = threadIdx.x; idx < 16384; idx += 256)
        t[(idx >> 7) * 130 + (idx & 127)] = f2bf(src[idx]);
    __syncthreads();
    ushort_t* d = Wt + r * 16384;
    for (int idx = threadIdx.x; idx < 16384; idx += 256)
        d[idx] = t[(idx & 127) * 130 + (idx >> 7)];
}

// ---------------- cast x (f32) -> compact bf16 [N,128] ----------------

__global__ void cast_x(const float* __restrict__ x, ushort_t* __restrict__ o, int total) {
    int i = (blockIdx.x * 256 + threadIdx.x) * 8;
    if (i >= total) return;
    float4 a = *(const float4*)(x + i);
    float4 b = *(const float4*)(x + i + 4);
    ushort_t t[8] = {f2bf(a.x), f2bf(a.y), f2bf(a.z), f2bf(a.w),
                     f2bf(b.x), f2bf(b.y), f2bf(b.z), f2bf(b.w)};
    *(int4v*)(o + i) = *(int4v*)t;
}

// ---------------- fused RGCN conv layer ----------------
// 128-node C-tile per block, 1024 threads (16 waves), 2 blocks/CU.
// Per r in 0..8: stage Wt[r] (async); build A-tile means in LDS (64 quarter-
// waves x 2 segments, linked-list walk, ds_write_b128); r==8 stages X rows
// async. Then 16x16x32 bf16 MFMA. LDS 16B-chunk c of row n at pos c^(n&15).

template <bool FINAL>
__global__ __launch_bounds__(1024) void fused_conv(
    const ushort_t* __restrict__ Xg,   // gather source [NPAD,128] bf16
    const int* __restrict__ head,      // [NPAD*8], -1 terminated
    const int* __restrict__ nxt, const int* __restrict__ esrc,
    const ushort_t* __restrict__ Wt,   // [9][128][128] bf16 (W^T per slot)
    const float* __restrict__ bias,
    float* __restrict__ outF, ushort_t* __restrict__ outBf, int N) {
    __shared__ ushort_t As[128 * 128];   // 32 KB
    __shared__ ushort_t Bs[128 * 128];   // 32 KB
    __shared__ int headS[1024];          // this block's (node,rel) heads, contiguous
    __shared__ float biasS[128];
    int tid = threadIdx.x;
    int wid = tid >> 6, lane = tid & 63;
    int l16 = lane & 15, q = lane >> 4;
    int qw = tid >> 4;                   // 0..63 quarter-wave id
    int nodeBase = blockIdx.x * 128;

    headS[tid] = head[nodeBase * RNUM + tid];   // coalesced 4 KB
    if (tid < 128) biasS[tid] = bias[tid];

    f32x4 acc[4];
#pragma unroll
    for (int ct = 0; ct < 4; ++ct) acc[ct] = (f32x4){0.f, 0.f, 0.f, 0.f};

    const ushort_t* gbase = Xg + (size_t)l16 * 8;

    for (int r = 0; r < 9; ++r) {
        __syncthreads();   // LDS free (prev MFMA reads done; 1st iter: headS ready)
        // stage B = Wt[r], 2048 x 16B slots, wave-contiguous LDS
#pragma unroll
        for (int i = 0; i < 2; ++i) {
            int L = i * 1024 + tid;
            int row = L >> 4;
            int c = (L & 15) ^ (row & 15);
            gl_lds16(Wt + r * 16384 + row * 128 + c * 8, (char*)Bs + (size_t)L * 16);
        }
        if (r == 8) {
            // root slot: A = X rows, async staged
#pragma unroll
            for (int i = 0; i < 2; ++i) {
                int L = i * 1024 + tid;
                int row = L >> 4;
                int c = (L & 15) ^ (row & 15);
                gl_lds16(Xg + (size_t)(nodeBase + row) * FDIM + c * 8,
                         (char*)As + (size_t)L * 16);
            }
        } else {
            // means: 2 segments per quarter-wave (overlaps with async B stage)
#pragma unroll
            for (int g = 0; g < 2; ++g) {
                int nl = qw * 2 + g;               // node-local row 0..127
                float acc0[8], acc1[8];
#pragma unroll
                for (int k = 0; k < 8; ++k) { acc0[k] = 0.f; acc1[k] = 0.f; }
                int cnt = 0;
                int j = headS[nl * RNUM + r];
                while (j >= 0) {
                    int s = esrc[j];               // independent: s + jn issue together
                    int jn = nxt[j];
                    int4v v = *(const int4v*)(gbase + (size_t)s * FDIM);
                    ushort_t* p = (ushort_t*)&v;
                    if (cnt & 1) {
#pragma unroll
                        for (int k = 0; k < 8; ++k) acc1[k] += bf2f(p[k]);
                    } else {
#pragma unroll
                        for (int k = 0; k < 8; ++k) acc0[k] += bf2f(p[k]);
                    }
                    ++cnt;
                    j = jn;
                }
                float sc = (cnt > 0) ? 1.0f / (float)cnt : 0.f;
                ushort_t ov[8];
#pragma unroll
                for (int k = 0; k < 8; ++k) ov[k] = f2bf((acc0[k] + acc1[k]) * sc);
                // swizzled store: lane l16 holds logical chunk l16 of row nl
                *(int4v*)((char*)As + nl * 256 + ((l16 ^ (nl & 15)) * 16)) = *(int4v*)ov;
            }
        }
        __syncthreads();   // drains vmcnt + lgkm -> tiles visible
        // MFMA: wave wid -> row-tile rw (16 rows), col half ch (4 x 16 cols)
        int rw = wid & 7, ch = wid >> 3;
#pragma unroll
        for (int s = 0; s < 4; ++s) {
            short8 a = *(const short8*)((const char*)As +
                        (rw * 16 + l16) * 256 + (((s * 4 + q) ^ l16) * 16));
#pragma unroll
            for (int ct = 0; ct < 4; ++ct) {
                int h = ch * 64 + ct * 16 + l16;
                short8 b = *(const short8*)((const char*)Bs +
                            h * 256 + (((s * 4 + q) ^ (h & 15)) * 16));
                acc[ct] = __builtin_amdgcn_mfma_f32_16x16x32_bf16(a, b, acc[ct], 0, 0, 0);
            }
        }
    }
    // epilogue: C layout col = lane&15, row = q*4 + reg
    int rw = wid & 7, ch = wid >> 3;
#pragma unroll
    for (int ct = 0; ct < 4; ++ct) {
        int h = ch * 64 + ct * 16 + l16;
        float bv = biasS[h];
#pragma unroll
        for (int reg = 0; reg < 4; ++reg) {
            int node = nodeBase + rw * 16 + q * 4 + reg;
            if (node < N) {
                float v = acc[ct][reg] + bv;
                if (FINAL) {
                    outF[(size_t)node * FDIM + h] = v;
                } else {
                    outBf[(size_t)node * FDIM + h] = f2bf(fmaxf(v, 0.f));
                }
            }
        }
    }
}

__global__ void copy_emb(const float* __restrict__ e, float* __restrict__ out, int n) {
    int i = blockIdx.x * 256 + threadIdx.x;
    if (i < n) out[i] = e[i];
}

// ---------------- launch ----------------

extern "C" void kernel_launch(void* const* d_in, const int* in_sizes, int n_in,
                              void* d_out, int out_size, void* d_ws, size_t ws_size,
                              hipStream_t stream) {
    const float* x        = (const float*)d_in[0];
    const int* edge_index = (const int*)d_in[1];
    const int* edge_type  = (const int*)d_in[2];
    const float* rel_w0   = (const float*)d_in[3];
    const float* root_w0  = (const float*)d_in[4];
    const float* bias0    = (const float*)d_in[5];
    const float* rel_w1   = (const float*)d_in[6];
    const float* root_w1  = (const float*)d_in[7];
    const float* bias1    = (const float*)d_in[8];
    const float* rel_emb  = (const float*)d_in[9];

    int N = in_sizes[0] / FDIM;   // 50000
    int E = in_sizes[1] / 2;      // 800000
    const int* src = edge_index;
    const int* dst = edge_index + E;

    int nb_conv = (N + 127) / 128;       // 391
    int NPAD = nb_conv * 128;            // 50048

    char* w = (char*)d_ws;
    auto alloc = [&](size_t bytes) -> char* {
        char* p = w;
        w += (bytes + 255) & ~(size_t)255;
        return p;
    };
    int* head      = (int*)alloc((size_t)NPAD * RNUM * 4);
    int* nxt       = (int*)alloc((size_t)E * 4);
    ushort_t* Wt   = (ushort_t*)alloc((size_t)2 * 9 * 16384 * 2);
    ushort_t* Xbf  = (ushort_t*)alloc((size_t)NPAD * FDIM * 2);
    ushort_t* hbuf = (ushort_t*)alloc((size_t)NPAD * FDIM * 2);
    (void)ws_size; (void)n_in; (void)out_size;

    int nb_E    = (E + 255) / 256;
    int nb_cast = (N * FDIM) / (256 * 8);   // 3125

    hipMemsetAsync(head, 0xFF, (size_t)NPAD * RNUM * 4, stream);   // all -1
    link_kernel<<<nb_E, 256, 0, stream>>>(dst, edge_type, head, nxt, E);
    transpose_w<<<9, 256, 0, stream>>>(rel_w0, root_w0, Wt);
    transpose_w<<<9, 256, 0, stream>>>(rel_w1, root_w1, Wt + 9 * 16384);
    cast_x<<<nb_cast, 256, 0, stream>>>(x, Xbf, N * FDIM);

    fused_conv<false><<<nb_conv, 1024, 0, stream>>>(Xbf, head, nxt, src, Wt, bias0,
                                                    nullptr, hbuf, N);
    fused_conv<true><<<nb_conv, 1024, 0, stream>>>(hbuf, head, nxt, src,
                                                   Wt + 9 * 16384, bias1,
                                                   (float*)d_out, nullptr, N);
    copy_emb<<<4, 256, 0, stream>>>(rel_emb, (float*)d_out + (size_t)N * FDIM,
                                    in_sizes[9]);
}

// Round 7
// 379.553 us; speedup vs baseline: 1.1304x; 1.1304x over previous
//
#include <hip/hip_runtime.h>

typedef unsigned short ushort_t;
typedef __attribute__((ext_vector_type(8))) short short8;
typedef __attribute__((ext_vector_type(4))) float f32x4;
typedef __attribute__((ext_vector_type(4))) int int4v;

#define RNUM 8
#define FDIM 128

__device__ __forceinline__ float bf2f(ushort_t u) {
    union { unsigned int i; float f; } x;
    x.i = ((unsigned int)u) << 16;
    return x.f;
}
__device__ __forceinline__ ushort_t f2bf(float f) {
    union { float f; unsigned int i; } x;
    x.f = f;
    unsigned int u = x.i;
    u += 0x7fffu + ((u >> 16) & 1u);   // round-to-nearest-even
    return (ushort_t)(u >> 16);
}

// async global->LDS, 16B per lane; LDS dest is wave-uniform base + lane*16
__device__ __forceinline__ void gl_lds16(const void* g, void* s) {
    __builtin_amdgcn_global_load_lds(
        (const __attribute__((address_space(1))) unsigned int*)g,
        (__attribute__((address_space(3))) unsigned int*)s, 16, 0, 0);
}

// ---------------- linked-list segment index (packed) ----------------
// head[seg] (memset -1) -> most recent edge id; nxt2[i] = {src, prev-edge}.
// One 8B random line per chain step instead of two 4B lines.

__global__ void link_kernel(const int* __restrict__ src, const int* __restrict__ dst,
                            const int* __restrict__ et, int* head,
                            int2* __restrict__ nxt2, int E) {
    int i = blockIdx.x * 256 + threadIdx.x;
    if (i < E) {
        int seg = dst[i] * RNUM + et[i];
        int old = atomicExch(&head[seg], i);
        nxt2[i] = make_int2(src[i], old);
    }
}

// ------- weight transpose + bf16 cast: Wt[l][r][h][f] = bf16(W[l][r][f][h]) -------

__global__ __launch_bounds__(256) void transpose_w(
    const float* __restrict__ rel_w0, const float* __restrict__ root_w0,
    const float* __restrict__ rel_w1, const float* __restrict__ root_w1,
    ushort_t* __restrict__ Wt) {
    int b = blockIdx.x;           // 0..17
    int layer = b / 9, r = b % 9;
    const float* src = (layer == 0) ? ((r < 8) ? (rel_w0 + r * 16384) : root_w0)
                                    : ((r < 8) ? (rel_w1 + r * 16384) : root_w1);
    __shared__ ushort_t t[128 * 130];
    for (int idx = threadIdx.x; idx < 16384; idx += 256)
        t[(idx >> 7) * 130 + (idx & 127)] = f2bf(src[idx]);
    __syncthreads();
    ushort_t* d = Wt + (size_t)b * 16384;
    for (int idx = threadIdx.x; idx < 16384; idx += 256)
        d[idx] = t[(idx & 127) * 130 + (idx >> 7)];
}

// ---------------- cast x (f32) -> compact bf16 [N,128] ----------------

__global__ void cast_x(const float* __restrict__ x, ushort_t* __restrict__ o, int total) {
    int i = (blockIdx.x * 256 + threadIdx.x) * 8;
    if (i >= total) return;
    float4 a = *(const float4*)(x + i);
    float4 b = *(const float4*)(x + i + 4);
    ushort_t t[8] = {f2bf(a.x), f2bf(a.y), f2bf(a.z), f2bf(a.w),
                     f2bf(b.x), f2bf(b.y), f2bf(b.z), f2bf(b.w)};
    *(int4v*)(o + i) = *(int4v*)t;
}

// ---------------- fused RGCN conv layer, register-resident means ----------------
// 64-node C-tile, 512 threads (8 waves), 2 blocks/CU (launch_bounds caps VGPR 128).
// Two passes of 4 relations: phase 1 walks 8 chains/quarter-wave accumulating
// means in REGISTERS (no barriers -> full latency overlap); phase 2 per r-slot:
// regs->LDS (swizzled), async-stage Wt[r], barrier, 4 MFMAs, barrier. Root slot
// staged async. LDS 16B-chunk c of row n stored at pos c^(n&15).

template <bool FINAL>
__global__ __launch_bounds__(512, 4) void fused_conv(
    const ushort_t* __restrict__ Xg,   // gather source [NPAD,128] bf16
    const int* __restrict__ head,      // [NPAD*8], -1 terminated
    const int2* __restrict__ nxt2,     // {src, next}
    const ushort_t* __restrict__ Wt,   // [9][128][128] bf16 (W^T per slot)
    const float* __restrict__ bias,
    float* __restrict__ outF, ushort_t* __restrict__ outBf, int N) {
    __shared__ ushort_t As[64 * 128];    // 16 KB
    __shared__ ushort_t Bs[128 * 128];   // 32 KB
    __shared__ int headS[512];           // 64 nodes x 8 rel
    __shared__ float biasS[128];
    int tid = threadIdx.x;
    int wid = tid >> 6, lane = tid & 63;
    int l16 = lane & 15, q = lane >> 4;
    int qw = tid >> 4;                   // 0..31
    int nodeBase = blockIdx.x * 64;
    int rw = wid & 3, ch = wid >> 2;

    headS[tid] = head[nodeBase * RNUM + tid];
    if (tid < 128) biasS[tid] = bias[tid];
    __syncthreads();

    f32x4 cacc[4];
#pragma unroll
    for (int ct = 0; ct < 4; ++ct) cacc[ct] = (f32x4){0.f, 0.f, 0.f, 0.f};

    const ushort_t* gbase = Xg + (size_t)l16 * 8;

#pragma unroll
    for (int p = 0; p < 2; ++p) {
        // ---- phase 1: barrier-free chain walks, means in registers ----
        float acc[8][8];
        int cnt[8];
#pragma unroll
        for (int c = 0; c < 8; ++c) {
            cnt[c] = 0;
#pragma unroll
            for (int k = 0; k < 8; ++k) acc[c][k] = 0.f;
        }
#pragma unroll
        for (int c = 0; c < 8; ++c) {
            int nl = qw * 2 + (c >> 2);        // node-local row
            int rr = p * 4 + (c & 3);          // relation
            int j = headS[nl * RNUM + rr];
            while (j >= 0) {
                int2 e = nxt2[j];              // one 8B line: {src, next}
                int4v v = *(const int4v*)(gbase + (size_t)e.x * FDIM);
                j = e.y;
                ushort_t* pv = (ushort_t*)&v;
#pragma unroll
                for (int k = 0; k < 8; ++k) acc[c][k] += bf2f(pv[k]);
                ++cnt[c];
            }
        }
        // ---- phase 2: 4 fast slot iterations ----
#pragma unroll
        for (int r2 = 0; r2 < 4; ++r2) {
            int r = p * 4 + r2;
            __syncthreads();                   // LDS free (prev MFMA reads done)
#pragma unroll
            for (int i = 0; i < 4; ++i) {      // stage Bs = Wt[r] (async, from L2)
                int L = i * 512 + tid;
                int row = L >> 4;
                int c = (L & 15) ^ (row & 15);
                gl_lds16(Wt + (size_t)r * 16384 + row * 128 + c * 8,
                         (char*)Bs + (size_t)L * 16);
            }
#pragma unroll
            for (int g = 0; g < 2; ++g) {      // regs -> A-slot
                int c = g * 4 + r2;
                int nl = qw * 2 + g;
                float sc = cnt[c] ? 1.0f / (float)cnt[c] : 0.f;
                ushort_t ov[8];
#pragma unroll
                for (int k = 0; k < 8; ++k) ov[k] = f2bf(acc[c][k] * sc);
                *(int4v*)((char*)As + nl * 256 + ((l16 ^ (nl & 15)) * 16)) = *(int4v*)ov;
            }
            __syncthreads();                   // drains vmcnt (B) + lgkm (A)
#pragma unroll
            for (int s = 0; s < 4; ++s) {
                short8 a = *(const short8*)((const char*)As +
                            (rw * 16 + l16) * 256 + (((s * 4 + q) ^ l16) * 16));
#pragma unroll
                for (int ct = 0; ct < 4; ++ct) {
                    int h = ch * 64 + ct * 16 + l16;
                    short8 b = *(const short8*)((const char*)Bs +
                                h * 256 + (((s * 4 + q) ^ l16) * 16));
                    cacc[ct] = __builtin_amdgcn_mfma_f32_16x16x32_bf16(a, b, cacc[ct], 0, 0, 0);
                }
            }
        }
    }
    // ---- root slot (r = 8): A = X rows, both tiles async staged ----
    __syncthreads();
#pragma unroll
    for (int i = 0; i < 4; ++i) {
        int L = i * 512 + tid;
        int row = L >> 4;
        int c = (L & 15) ^ (row & 15);
        gl_lds16(Wt + (size_t)8 * 16384 + row * 128 + c * 8, (char*)Bs + (size_t)L * 16);
    }
#pragma unroll
    for (int i = 0; i < 2; ++i) {
        int L = i * 512 + tid;                 // 0..1023 (64 rows x 16 chunks)
        int row = L >> 4;
        int c = (L & 15) ^ (row & 15);
        gl_lds16(Xg + (size_t)(nodeBase + row) * FDIM + c * 8, (char*)As + (size_t)L * 16);
    }
    __syncthreads();
#pragma unroll
    for (int s = 0; s < 4; ++s) {
        short8 a = *(const short8*)((const char*)As +
                    (rw * 16 + l16) * 256 + (((s * 4 + q) ^ l16) * 16));
#pragma unroll
        for (int ct = 0; ct < 4; ++ct) {
            int h = ch * 64 + ct * 16 + l16;
            short8 b = *(const short8*)((const char*)Bs +
                        h * 256 + (((s * 4 + q) ^ l16) * 16));
            cacc[ct] = __builtin_amdgcn_mfma_f32_16x16x32_bf16(a, b, cacc[ct], 0, 0, 0);
        }
    }
    // ---- epilogue: C layout col = lane&15, row = q*4 + reg ----
#pragma unroll
    for (int ct = 0; ct < 4; ++ct) {
        int h = ch * 64 + ct * 16 + l16;
        float bv = biasS[h];
#pragma unroll
        for (int reg = 0; reg < 4; ++reg) {
            int node = nodeBase + rw * 16 + q * 4 + reg;
            if (node < N) {
                float v = cacc[ct][reg] + bv;
                if (FINAL) {
                    outF[(size_t)node * FDIM + h] = v;
                } else {
                    outBf[(size_t)node * FDIM + h] = f2bf(fmaxf(v, 0.f));
                }
            }
        }
    }
}

__global__ void copy_emb(const float* __restrict__ e, float* __restrict__ out, int n) {
    int i = blockIdx.x * 256 + threadIdx.x;
    if (i < n) out[i] = e[i];
}

// ---------------- launch ----------------

extern "C" void kernel_launch(void* const* d_in, const int* in_sizes, int n_in,
                              void* d_out, int out_size, void* d_ws, size_t ws_size,
                              hipStream_t stream) {
    const float* x        = (const float*)d_in[0];
    const int* edge_index = (const int*)d_in[1];
    const int* edge_type  = (const int*)d_in[2];
    const float* rel_w0   = (const float*)d_in[3];
    const float* root_w0  = (const float*)d_in[4];
    const float* bias0    = (const float*)d_in[5];
    const float* rel_w1   = (const float*)d_in[6];
    const float* root_w1  = (const float*)d_in[7];
    const float* bias1    = (const float*)d_in[8];
    const float* rel_emb  = (const float*)d_in[9];

    int N = in_sizes[0] / FDIM;   // 50000
    int E = in_sizes[1] / 2;      // 800000
    const int* src = edge_index;
    const int* dst = edge_index + E;

    int nb_conv = (N + 63) / 64;         // 782
    int NPAD = nb_conv * 64;             // 50048

    char* w = (char*)d_ws;
    auto alloc = [&](size_t bytes) -> char* {
        char* p = w;
        w += (bytes + 255) & ~(size_t)255;
        return p;
    };
    int* head      = (int*)alloc((size_t)NPAD * RNUM * 4);
    int2* nxt2     = (int2*)alloc((size_t)E * 8);
    ushort_t* Wt   = (ushort_t*)alloc((size_t)2 * 9 * 16384 * 2);
    ushort_t* Xbf  = (ushort_t*)alloc((size_t)NPAD * FDIM * 2);
    ushort_t* hbuf = (ushort_t*)alloc((size_t)NPAD * FDIM * 2);
    (void)ws_size; (void)n_in; (void)out_size;

    int nb_E    = (E + 255) / 256;
    int nb_cast = (N * FDIM) / (256 * 8);   // 3125

    hipMemsetAsync(head, 0xFF, (size_t)NPAD * RNUM * 4, stream);   // all -1
    link_kernel<<<nb_E, 256, 0, stream>>>(src, dst, edge_type, head, nxt2, E);
    transpose_w<<<18, 256, 0, stream>>>(rel_w0, root_w0, rel_w1, root_w1, Wt);
    cast_x<<<nb_cast, 256, 0, stream>>>(x, Xbf, N * FDIM);

    fused_conv<false><<<nb_conv, 512, 0, stream>>>(Xbf, head, nxt2, Wt, bias0,
                                                   nullptr, hbuf, N);
    fused_conv<true><<<nb_conv, 512, 0, stream>>>(hbuf, head, nxt2,
                                                  Wt + 9 * 16384, bias1,
                                                  (float*)d_out, nullptr, N);
    copy_emb<<<4, 256, 0, stream>>>(rel_emb, (float*)d_out + (size_t)N * FDIM,
                                    in_sizes[9]);
}